// Round 3
// baseline (2278.370 us; speedup 1.0000x reference)
//
#include <hip/hip_runtime.h>

typedef unsigned short u16;
typedef __bf16 bf16x8 __attribute__((ext_vector_type(8)));
typedef float f32x4 __attribute__((ext_vector_type(4)));

#define BM 128
#define BN 128
#define BK 32
#define SE 40  // LDS row stride (elements): 80B rows -> 16B aligned, spreads banks

__device__ __forceinline__ float bf2f(u16 u) {
    return __uint_as_float(((unsigned int)u) << 16);
}
__device__ __forceinline__ u16 f2bf(float f) {
    unsigned int x = __float_as_uint(f);
    return (u16)((x + 0x7fffu + ((x >> 16) & 1u)) >> 16);  // RNE (no NaN inputs in this pipeline)
}

// Load 8 contiguous elements as bf16 into d[0..7]; converts if source is f32.
__device__ __forceinline__ void ld8(const u16* p, u16* d) {
    *(uint4*)d = *(const uint4*)p;
}
__device__ __forceinline__ void ld8(const float* p, u16* d) {
    float4 a = *(const float4*)p;
    float4 b = *(const float4*)(p + 4);
    d[0] = f2bf(a.x); d[1] = f2bf(a.y); d[2] = f2bf(a.z); d[3] = f2bf(a.w);
    d[4] = f2bf(b.x); d[5] = f2bf(b.y); d[6] = f2bf(b.z); d[7] = f2bf(b.w);
}

__device__ __forceinline__ void stC(u16* p, float v)  { *p = f2bf(v); }
__device__ __forceinline__ void stC(float* p, float v){ *p = v; }

// Generic MFMA GEMM, bf16 compute: C[M,N] = A[M,K] * B  (B [K,N] if !BT, [N,K] if BT)
// aMode/bMode: 0 -> base += strideZ*bz ; 1/2/3 -> qkv head-column offset for q/v/k
//   (head hz = bz + zBase, col = (hz>>2)*3072 + (hz&3)*256 + (mode-1)*1024)
// causal: 0 none; 1 skip blocks bx>by (scores); 2 limit K to (by+1)*BM (PV)
template <bool BT, typename TA, typename TB, typename TC>
__global__ __launch_bounds__(256) void gemm_bf16(
    const TA* __restrict__ A, long strideAz, int aMode, int lda,
    const TB* __restrict__ B, long strideBz, int bMode, int ldb,
    TC* __restrict__ C, long strideCz, int ldc,
    int K, int causal, int zBase)
{
    const int bx = blockIdx.x, by = blockIdx.y, bz = blockIdx.z;
    if (causal == 1 && bx > by) return;
    int kLen = K;
    if (causal == 2) { int kl = (by + 1) * BM; kLen = kl < K ? kl : K; }

    const int hz = bz + zBase;
    const long hoff = (long)((hz >> 2) * 3072 + (hz & 3) * 256);
    const TA* Ab = A + (aMode == 0 ? strideAz * bz : hoff + (long)(aMode - 1) * 1024);
    const TB* Bb = B + (bMode == 0 ? strideBz * bz : hoff + (long)(bMode - 1) * 1024);
    TC* Cb = C + strideCz * bz;

    __shared__ __align__(16) u16 As[BM][SE];
    __shared__ __align__(16) u16 Bs[BN][SE];

    const int tid  = threadIdx.x;
    const int lane = tid & 63;
    const int wave = tid >> 6;
    const int quad = lane >> 4;
    const int l16  = lane & 15;
    const int mBase = (wave >> 1) * 64;
    const int nBase = (wave & 1) * 64;

    const int row0 = by * BM;
    const int col0 = bx * BN;

    const int ar = tid >> 2;         // A staging: row (and row+64)
    const int ac = (tid & 3) * 8;    // A staging: col8
    const int bk = tid & 15;         // B staging (!BT): k (and k+16)
    const int bg = tid >> 4;         // B staging (!BT): n-group (8 cols)

    f32x4 acc[4][4] = {};

    for (int k0 = 0; k0 < kLen; k0 += BK) {
        {
            u16 t0[8], t1[8];
            ld8(Ab + (long)(row0 + ar) * lda + (k0 + ac), t0);
            ld8(Ab + (long)(row0 + ar + 64) * lda + (k0 + ac), t1);
            *(uint4*)(&As[ar][ac])      = *(uint4*)t0;
            *(uint4*)(&As[ar + 64][ac]) = *(uint4*)t1;
        }
        if (BT) {
            u16 t0[8], t1[8];
            ld8(Bb + (long)(col0 + ar) * ldb + (k0 + ac), t0);
            ld8(Bb + (long)(col0 + ar + 64) * ldb + (k0 + ac), t1);
            *(uint4*)(&Bs[ar][ac])      = *(uint4*)t0;
            *(uint4*)(&Bs[ar + 64][ac]) = *(uint4*)t1;
        } else {
            u16 s0[8], s1[8];
            ld8(Bb + (long)(k0 + bk) * ldb + (col0 + bg * 8), s0);
            ld8(Bb + (long)(k0 + bk + 16) * ldb + (col0 + bg * 8), s1);
            #pragma unroll
            for (int j = 0; j < 8; ++j) {
                const int jj = (j + 2 * bg) & 7;  // rotate -> 2-way banks (free)
                Bs[bg * 8 + jj][bk]      = s0[jj];
                Bs[bg * 8 + jj][bk + 16] = s1[jj];
            }
        }
        __syncthreads();

        bf16x8 af[4], bfr[4];
        #pragma unroll
        for (int i = 0; i < 4; ++i)
            af[i] = *(const bf16x8*)(&As[mBase + 16 * i + l16][quad * 8]);
        #pragma unroll
        for (int j = 0; j < 4; ++j)
            bfr[j] = *(const bf16x8*)(&Bs[nBase + 16 * j + l16][quad * 8]);
        #pragma unroll
        for (int i = 0; i < 4; ++i)
            #pragma unroll
            for (int j = 0; j < 4; ++j)
                acc[i][j] = __builtin_amdgcn_mfma_f32_16x16x32_bf16(af[i], bfr[j], acc[i][j], 0, 0, 0);
        __syncthreads();
    }

    #pragma unroll
    for (int i = 0; i < 4; ++i) {
        const int r0 = row0 + mBase + 16 * i + quad * 4;  // C/D: row = quad*4+reg
        #pragma unroll
        for (int j = 0; j < 4; ++j) {
            const int c = col0 + nBase + 16 * j + l16;    // C/D: col = lane&15
            #pragma unroll
            for (int r = 0; r < 4; ++r)
                stC(&Cb[(long)(r0 + r) * ldc + c], acc[i][j][r]);
        }
    }
}

// In-place GPT-J rotary on q,k (first 64 dims of each head) + fold 1/sqrt(D)=1/16 into q.
// qkv row layout per mp chunk of 3072: [q 1024 | v 1024 | k 1024], head col = sub*256.
__global__ __launch_bounds__(256) void rotary_kernel(u16* __restrict__ qkv,
                                                     const int* __restrict__ pos_ids)
{
    const long bs = blockIdx.x;  // 0..S-1 (per-batch launch)
    const float pos = (float)pos_ids[bs];
    u16* row = qkv + bs * 12288;
    for (int idx = threadIdx.x; idx < 16 * 224; idx += 256) {
        const int h = idx / 224;
        const int r = idx - h * 224;
        const int base = (h >> 2) * 3072 + (h & 3) * 256;
        if (r < 32) {
            const float invf = powf(10000.0f, (-2.0f * (float)r) * (1.0f / 64.0f));
            float s, c;
            sincosf(pos * invf, &s, &c);
            const int d0 = base + 2 * r;
            const int k0 = d0 + 2048;
            float q0 = bf2f(row[d0]), q1 = bf2f(row[d0 + 1]);
            float ka = bf2f(row[k0]), kb = bf2f(row[k0 + 1]);
            row[d0]     = f2bf((q0 * c - q1 * s) * 0.0625f);
            row[d0 + 1] = f2bf((q1 * c + q0 * s) * 0.0625f);
            row[k0]     = f2bf(ka * c - kb * s);
            row[k0 + 1] = f2bf(kb * c + ka * s);
        } else {
            const int d = base + 64 + (r - 32);
            row[d] = f2bf(bf2f(row[d]) * 0.0625f);  // exact in bf16
        }
    }
}

// Causal row softmax over scores[h][qi][0..S-1] (valid j<=qi), writes zeros for j>qi.
__global__ __launch_bounds__(256) void softmax_kernel(u16* __restrict__ scores)
{
    const int qi = blockIdx.x;
    const int h  = blockIdx.y;
    u16* row = scores + ((long)h * 2048 + qi) * 2048;
    const int tid = threadIdx.x;
    const int n = qi + 1;

    float vals[8];
    float lmax = -3.0e38f;
    #pragma unroll
    for (int i = 0; i < 8; ++i) {
        const int j = tid + i * 256;
        const float v = (j < n) ? bf2f(row[j]) : -3.0e38f;
        vals[i] = v;
        lmax = fmaxf(lmax, v);
    }
    __shared__ float red[4];
    #pragma unroll
    for (int off = 32; off > 0; off >>= 1) lmax = fmaxf(lmax, __shfl_down(lmax, off));
    if ((tid & 63) == 0) red[tid >> 6] = lmax;
    __syncthreads();
    lmax = fmaxf(fmaxf(red[0], red[1]), fmaxf(red[2], red[3]));

    float lsum = 0.f;
    #pragma unroll
    for (int i = 0; i < 8; ++i) {
        const int j = tid + i * 256;
        const float e = (j < n) ? expf(vals[i] - lmax) : 0.f;
        vals[i] = e;
        lsum += e;
    }
    #pragma unroll
    for (int off = 32; off > 0; off >>= 1) lsum += __shfl_down(lsum, off);
    __syncthreads();
    if ((tid & 63) == 0) red[tid >> 6] = lsum;
    __syncthreads();
    lsum = red[0] + red[1] + red[2] + red[3];
    const float inv = 1.0f / lsum;
    #pragma unroll
    for (int i = 0; i < 8; ++i)
        row[tid + i * 256] = f2bf(vals[i] * inv);
}

extern "C" void kernel_launch(void* const* d_in, const int* in_sizes, int n_in,
                              void* d_out, int out_size, void* d_ws, size_t ws_size,
                              hipStream_t stream)
{
    const float* hidden = (const float*)d_in[0];
    const float* w_qkv  = (const float*)d_in[1];
    const float* w_out  = (const float*)d_in[2];
    const int*   pos    = (const int*)d_in[3];
    float* out = (float*)d_out;

    const int Bn = 2, S = 2048, E = 4096, H = 16;
    const int N3 = 3 * E;    // 12288

    // Per-batch ws layout (bf16): qkv_b (48MiB) | attn_b (16MiB) | sc (hc * 8MiB)
    u16* qkvb  = (u16*)d_ws;
    u16* attnb = qkvb + (size_t)S * N3;
    u16* sc    = attnb + (size_t)S * E;

    const size_t need_base = ((size_t)S * N3 + (size_t)S * E) * 2;  // 64 MiB
    const size_t per_head  = (size_t)S * S * 2;                     // 8 MiB
    int hc = 1;
    if (ws_size > need_base) {
        size_t avail = ws_size - need_base;
        hc = (int)(avail / per_head);
        if (hc < 1) hc = 1;
        if (hc > H) hc = H;
        while (H % hc) --hc;   // hc in {16,8,4,2,1}
    }

    dim3 blk(256);

    for (int b = 0; b < Bn; ++b) {
        // 1. QKV projection for batch b: f32 in, bf16 out: [2048,4096] x [4096,12288]
        gemm_bf16<false><<<dim3(N3 / BN, S / BM, 1), blk, 0, stream>>>(
            hidden + (size_t)b * S * E, 0L, 0, E,
            w_qkv, 0L, 0, N3,
            qkvb, 0L, N3, E, 0, 0);

        // 2. rotary (+ q *= 1/16) in place on bf16 qkv
        rotary_kernel<<<dim3(S), blk, 0, stream>>>(qkvb, pos + (size_t)b * S);

        // 3. attention, head-chunked to fit ws
        for (int h0 = 0; h0 < H; h0 += hc) {
            // scores = Qs * K^T  (K slice is [S, D] row-major inside qkv -> BT)
            gemm_bf16<true><<<dim3(S / BN, S / BM, hc), blk, 0, stream>>>(
                qkvb, 0L, 1, N3,
                qkvb, 0L, 3, N3,
                sc, (long)S * S, S,
                256, 1, h0);
            softmax_kernel<<<dim3(S, hc), blk, 0, stream>>>(sc);
            // attn[s, h*256+d] = P * V   (V slice [S, D] row-major -> !BT)
            gemm_bf16<false><<<dim3(2, S / BM, hc), blk, 0, stream>>>(
                sc, (long)S * S, 0, S,
                qkvb, 0L, 2, N3,
                attnb + (size_t)h0 * 256, 256L, E,
                S, 2, h0);
        }

        // 4. output projection: bf16 x f32 -> f32 out: [2048,4096] x [4096,4096]
        gemm_bf16<false><<<dim3(E / BN, S / BM, 1), blk, 0, stream>>>(
            attnb, 0L, 0, E,
            w_out, 0L, 0, E,
            out + (size_t)b * S * E, 0L, E, E, 0, 0);
    }
}